// Round 1
// 269.856 us; speedup vs baseline: 1.0796x; 1.0796x over previous
//
#include <hip/hip_runtime.h>
#include <math.h>

// Probabilistic Slot Attention, B=8 N=4096 K=8 D=256, 3 iterations.
// Round 3: (1) LN + bf16 hi/lo split hoisted out of the GEMM into k_lnprep
// (writes xh/xl planes) so k_gemm stages BOTH operands via width-16
// global_load_lds (pure MFMA pipeline, no per-tile LN/f2bf VALU).
// (2) Occupancy: k_gll 256->512 blocks (4-way D split + LDS combine),
// k_mus2 256->512 blocks (NSPLIT=64, 64-n chunks), k_softmax 1024 threads.

#define Bd 8
#define Nd 4096
#define Kd 8
#define Dd 256
#define Md (Bd*Nd)              // 32768 rows
#define NITER 3
#define EPSf 1e-8f
#define LNEPS 1e-5f
#define NSPLIT 64
#define NCHUNK 64
#define LOGNORM -235.24826450039617f   // -0.5*256*log(2*pi)

typedef float f32x4 __attribute__((ext_vector_type(4)));
typedef short bf16x8 __attribute__((ext_vector_type(8)));
typedef unsigned short ushort_t;
typedef unsigned short us4 __attribute__((ext_vector_type(4)));

// workspace float offsets
#define KEYS_OFF 0
#define VALS_OFF (Md*Dd)
#define GLL_OFF  (2*Md*Dd)
#define Q_OFF    (GLL_OFF + Bd*Kd*Nd)
#define W_OFF    (Q_OFF + Bd*Kd*Dd)
#define CST_OFF  (W_OFF + Bd*Kd*Dd)
#define PART_OFF (CST_OFF + 64)
#define PARTSZ   (Bd*NSPLIT*Kd*Dd)
#define WH_OFF   (PART_OFF + 2*PARTSZ)   // ushort[512*256] == 65536 floats
#define WL_OFF   (WH_OFF + 65536)
#define XPLANE   (Md*Dd/2)               // ushort[32768*256] == 4194304 floats
#define XH_OFF   (WL_OFF + 65536)
#define XL_OFF   (XH_OFF + XPLANE)
#define WS_TOTAL (XL_OFF + XPLANE)

__device__ __forceinline__ ushort_t f2bf(float f) {
    unsigned u = __float_as_uint(f);
    return (ushort_t)((u + 0x7FFFu + ((u >> 16) & 1u)) >> 16);   // RNE
}
__device__ __forceinline__ float b2f(ushort_t h) {
    return __uint_as_float(((unsigned)h) << 16);
}
__device__ __forceinline__ void gload_lds16(const void* g, void* l) {
    __builtin_amdgcn_global_load_lds(
        (__attribute__((address_space(1))) void*)g,
        (__attribute__((address_space(3))) void*)l, 16, 0, 0);
}

// ---------------------------------------------------------------------------
// LN + bf16 hi/lo split, written once. 1024 blocks x 256 thr, wave = 8 rows.
// xh/xl are [32768][256] bf16 row-major. Numerics identical to the previous
// in-GEMM staging (fp32 LN, RNE split).
__global__ __launch_bounds__(256) void k_lnprep(
        const float* __restrict__ emb, const float* __restrict__ lns,
        const float* __restrict__ lnb, ushort_t* __restrict__ xh,
        ushort_t* __restrict__ xl) {
    const int tid = threadIdx.x, wave = tid >> 6, lane = tid & 63;
    const int row0 = blockIdx.x * 32;
    const float4 sc = ((const float4*)lns)[lane];
    const float4 bi = ((const float4*)lnb)[lane];
    for (int rr = 0; rr < 8; ++rr) {
        const int r = row0 + wave * 8 + rr;
        const float4 e4 = ((const float4*)(emb + (size_t)r * Dd))[lane];
        float s = e4.x + e4.y + e4.z + e4.w;
        #pragma unroll
        for (int off = 32; off; off >>= 1) s += __shfl_xor(s, off);
        const float m = s * (1.0f / 256.0f);
        const float dx = e4.x - m, dy = e4.y - m, dz = e4.z - m, dw = e4.w - m;
        float ss = dx * dx + dy * dy + dz * dz + dw * dw;
        #pragma unroll
        for (int off = 32; off; off >>= 1) ss += __shfl_xor(ss, off);
        const float rs = 1.0f / sqrtf(ss * (1.0f / 256.0f) + LNEPS);
        float x[4];
        x[0] = dx * rs * sc.x + bi.x;
        x[1] = dy * rs * sc.y + bi.y;
        x[2] = dz * rs * sc.z + bi.z;
        x[3] = dw * rs * sc.w + bi.w;
        us4 h4, l4;
        #pragma unroll
        for (int j = 0; j < 4; ++j) {
            const ushort_t h = f2bf(x[j]);
            h4[j] = h;
            l4[j] = f2bf(x[j] - b2f(h));
        }
        *(us4*)(xh + (size_t)r * Dd + lane * 4) = h4;
        *(us4*)(xl + (size_t)r * Dd + lane * 4) = l4;
    }
}

// ---------------------------------------------------------------------------
// Split Wk||Wv (512 x 256) into bf16 hi/lo planes.
__global__ __launch_bounds__(256) void k_wsplit(
        const float* __restrict__ Wk, const float* __restrict__ Wv,
        ushort_t* __restrict__ Wh, ushort_t* __restrict__ Wl) {
    const int r = blockIdx.x, d = threadIdx.x;
    const float w = (r < 256) ? Wk[(size_t)r * 256 + d] : Wv[(size_t)(r - 256) * 256 + d];
    const ushort_t h = f2bf(w);
    Wh[(size_t)r * 256 + d] = h;
    Wl[(size_t)r * 256 + d] = f2bf(w - b2f(h));
}

// ---------------------------------------------------------------------------
// GEMM: C[32768 x 512] = x x [Wk||Wv]^T via split-bf16 MFMA (xh*Wh + xh*Wl +
// xl*Wh). Block tile 128(M) x 256(N), BK=32, 4 waves 2x2, wave tile 64x128.
// Both operands staged with width-16 global_load_lds; LDS granule (row r,
// slot g') holds k-granule g = g' ^ ((r>>1)&3) (XOR swizzle, conflict-free
// b128 frag reads, lane-contiguous LDS order for global_load_lds).
__global__ __launch_bounds__(256, 2) void k_gemm(
        const ushort_t* __restrict__ xh, const ushort_t* __restrict__ xl,
        const ushort_t* __restrict__ Wh, const ushort_t* __restrict__ Wl,
        float* __restrict__ keys, float* __restrict__ vals) {
    __shared__ ushort_t Ah[128 * 32], Al[128 * 32];   // 8 KB each
    __shared__ ushort_t Bh[256 * 32], Bl[256 * 32];   // 16 KB each
    const int tid = threadIdx.x, lane = tid & 63, wave = tid >> 6;
    const int row0 = blockIdx.x * 128;
    const int cb = blockIdx.y;                 // 0 -> keys, 1 -> vals
    const int wm = wave >> 1, wn = wave & 1;

    f32x4 acc[4][8];
    #pragma unroll
    for (int a = 0; a < 4; ++a)
        #pragma unroll
        for (int b = 0; b < 8; ++b) acc[a][b] = (f32x4)(0.0f);

    for (int jb = 0; jb < 256; jb += 32) {
        // ---- A staging: global_load_lds width=16, swizzled source ----
        #pragma unroll
        for (int i = 0; i < 2; ++i) {
            const int p = tid + i * 256;            // granule 0..511
            const int r = p >> 2, gp = p & 3;
            const int g = gp ^ ((r >> 1) & 3);
            const size_t goff = (size_t)(row0 + r) * 256 + jb + g * 8;
            gload_lds16(xh + goff, &Ah[p * 8]);
            gload_lds16(xl + goff, &Al[p * 8]);
        }
        // ---- B staging: global_load_lds width=16, swizzled source ----
        #pragma unroll
        for (int i = 0; i < 4; ++i) {
            const int p = (wave * 4 + i) * 64 + lane;   // granule 0..1023
            const int r = p >> 2, gp = p & 3;
            const int g = gp ^ ((r >> 1) & 3);
            const size_t goff = (size_t)(cb * 256 + r) * 256 + jb + g * 8;
            gload_lds16(Wh + goff, &Bh[p * 8]);
            gload_lds16(Wl + goff, &Bl[p * 8]);
        }
        __syncthreads();

        // ---- compute ----
        bf16x8 bhf[8], blf[8];
        #pragma unroll
        for (int ni = 0; ni < 8; ++ni) {
            const int c = wn * 128 + ni * 16 + (lane & 15);
            const int g = lane >> 4;
            const int off = c * 32 + ((g ^ ((c >> 1) & 3)) << 3);
            bhf[ni] = *(const bf16x8*)&Bh[off];
            blf[ni] = *(const bf16x8*)&Bl[off];
        }
        #pragma unroll
        for (int mi = 0; mi < 4; ++mi) {
            const int rr = wm * 64 + mi * 16 + (lane & 15);
            const int g = lane >> 4;
            const int off = rr * 32 + ((g ^ ((rr >> 1) & 3)) << 3);
            const bf16x8 ah = *(const bf16x8*)&Ah[off];
            const bf16x8 al = *(const bf16x8*)&Al[off];
            #pragma unroll
            for (int ni = 0; ni < 8; ++ni) {
                acc[mi][ni] = __builtin_amdgcn_mfma_f32_16x16x32_bf16(ah, bhf[ni], acc[mi][ni], 0, 0, 0);
                acc[mi][ni] = __builtin_amdgcn_mfma_f32_16x16x32_bf16(ah, blf[ni], acc[mi][ni], 0, 0, 0);
                acc[mi][ni] = __builtin_amdgcn_mfma_f32_16x16x32_bf16(al, bhf[ni], acc[mi][ni], 0, 0, 0);
            }
        }
        __syncthreads();
    }
    // ---- epilogue: C/D layout col=lane&15, row=(lane>>4)*4+reg ----
    float* outp = (cb == 0) ? keys : vals;
    #pragma unroll
    for (int mi = 0; mi < 4; ++mi) {
        const int rbase = row0 + wm * 64 + mi * 16 + ((lane >> 4) << 2);
        #pragma unroll
        for (int ni = 0; ni < 8; ++ni) {
            const int col = wn * 128 + ni * 16 + (lane & 15);
            #pragma unroll
            for (int rg = 0; rg < 4; ++rg)
                outp[(size_t)(rbase + rg) * Dd + col] = acc[mi][ni][rg];
        }
    }
}

// ---------------------------------------------------------------------------
// init: queries = (mu0 + exp(lsig)*noise_init) @ Wq^T, iteration-0 w & cst.
__global__ __launch_bounds__(256) void k_init(
        const float* __restrict__ mu0, const float* __restrict__ lsig,
        const float* __restrict__ nz0, const float* __restrict__ Wq,
        float* __restrict__ qout, float* __restrict__ w_ws,
        float* __restrict__ cst_ws) {
    __shared__ float s_s[256];
    __shared__ float red[256];
    const int bk = blockIdx.x;
    const int k = bk & 7;
    const int d = threadIdx.x;
    const float sg = expf(lsig[k * 256 + d]);
    s_s[d] = mu0[k * 256 + d] + sg * nz0[(size_t)bk * 256 + d];
    w_ws[(size_t)bk * 256 + d] = 1.0f / (sg * sg + EPSf);
    red[d] = logf(fabsf(sg) + EPSf);
    __syncthreads();
    for (int s = 128; s; s >>= 1) {
        if (d < s) red[d] += red[d + s];
        __syncthreads();
    }
    if (d == 0) cst_ws[bk] = LOGNORM - 0.5f * red[0];

    float acc = 0.0f;
    const float4* Wr = (const float4*)(Wq + (size_t)d * 256);
    const float4* sp = (const float4*)s_s;
    #pragma unroll 8
    for (int j = 0; j < 64; ++j) {
        const float4 w4 = Wr[j], s4 = sp[j];
        acc += w4.x * s4.x + w4.y * s4.y + w4.z * s4.z + w4.w * s4.w;
    }
    qout[(size_t)bk * 256 + d] = acc;
}

// ---------------------------------------------------------------------------
// gll[b,k,n] = clip(cst - 0.5*sum_d (keys-q)^2 * w, +-1e4).
// 512 blocks x 256 thr: 4 waves split D into quarters (64 floats each),
// 64 n-rows per block, LDS combine. 2 blocks/CU -> 8 waves/CU.
__global__ __launch_bounds__(256) void k_gll(
        const float* __restrict__ keys, const float* __restrict__ q_ws,
        const float* __restrict__ w_ws, const float* __restrict__ cst_ws,
        float* __restrict__ gll) {
    __shared__ float part[3][8][64];
    const int bx = blockIdx.x;
    const int b = bx >> 6, chunk = bx & 63;
    const int tid = threadIdx.x, nloc = tid & 63, dh = tid >> 6;
    const int n = chunk * 64 + nloc;
    const float4* krow = (const float4*)(keys + ((size_t)b * Nd + n) * Dd) + dh * 16;
    const float4* qb = (const float4*)(q_ws + (size_t)b * Kd * Dd) + dh * 16;
    const float4* wb = (const float4*)(w_ws + (size_t)b * Kd * Dd) + dh * 16;
    float acc[8];
    #pragma unroll
    for (int kk = 0; kk < 8; ++kk) acc[kk] = 0.0f;
    #pragma unroll
    for (int dq = 0; dq < 16; ++dq) {
        const float4 k4 = krow[dq];
        #pragma unroll
        for (int kk = 0; kk < 8; ++kk) {
            const float4 q4 = qb[kk * 64 + dq];
            const float4 w4 = wb[kk * 64 + dq];
            float t;
            t = k4.x - q4.x; acc[kk] += t * t * w4.x;
            t = k4.y - q4.y; acc[kk] += t * t * w4.y;
            t = k4.z - q4.z; acc[kk] += t * t * w4.z;
            t = k4.w - q4.w; acc[kk] += t * t * w4.w;
        }
    }
    if (dh) {
        #pragma unroll
        for (int kk = 0; kk < 8; ++kk) part[dh - 1][kk][nloc] = acc[kk];
    }
    __syncthreads();
    if (dh == 0) {
        #pragma unroll
        for (int kk = 0; kk < 8; ++kk) {
            float g = cst_ws[b * Kd + kk]
                    - 0.5f * (acc[kk] + part[0][kk][nloc]
                              + part[1][kk][nloc] + part[2][kk][nloc]);
            g = fminf(fmaxf(g, -10000.0f), 10000.0f);
            gll[((size_t)(b * Kd + kk)) * Nd + n] = g;
        }
    }
}

// ---------------------------------------------------------------------------
// softmax over N per (b,k); writes attn in (B,K,N) layout into d_out.
// 64 blocks x 1024 thr: one float4 per thread, wave + LDS reduce.
__global__ __launch_bounds__(1024) void k_softmax(
        const float* __restrict__ gll, float* __restrict__ attn) {
    __shared__ float wred[16];
    __shared__ float wsum[16];
    const int bk = blockIdx.x, tid = threadIdx.x;
    const int lane = tid & 63, wave = tid >> 6;
    const float4 v = ((const float4*)(gll + (size_t)bk * Nd))[tid];
    float mx = fmaxf(fmaxf(v.x, v.y), fmaxf(v.z, v.w));
    #pragma unroll
    for (int off = 32; off; off >>= 1) mx = fmaxf(mx, __shfl_xor(mx, off));
    if (lane == 0) wred[wave] = mx;
    __syncthreads();
    mx = wred[0];
    #pragma unroll
    for (int i = 1; i < 16; ++i) mx = fmaxf(mx, wred[i]);
    float4 e;
    e.x = expf(v.x - mx); e.y = expf(v.y - mx);
    e.z = expf(v.z - mx); e.w = expf(v.w - mx);
    float sum = e.x + e.y + e.z + e.w;
    #pragma unroll
    for (int off = 32; off; off >>= 1) sum += __shfl_xor(sum, off);
    if (lane == 0) wsum[wave] = sum;
    __syncthreads();
    float tot = 0.0f;
    #pragma unroll
    for (int i = 0; i < 16; ++i) tot += wsum[i];
    const float inv = 1.0f / tot;
    float4 o;
    o.x = e.x * inv; o.y = e.y * inv; o.z = e.z * inv; o.w = e.w * inv;
    ((float4*)(attn + (size_t)bk * Nd))[tid] = o;
}

// ---------------------------------------------------------------------------
// partial mu / E[v^2] over an n-chunk. 512 blocks (b x 64 splits of 64 n).
__global__ __launch_bounds__(256) void k_mus2(
        const float* __restrict__ vals, const float* __restrict__ attn,
        float* __restrict__ part) {
    __shared__ float a_s[8][NCHUNK];
    const int blk = blockIdx.x;
    const int b = blk >> 6, s = blk & 63;
    const int n0 = s * NCHUNK;
    const int tid = threadIdx.x;
    #pragma unroll
    for (int i = 0; i < 2; ++i) {
        const int f = i * 256 + tid;
        const int k = f >> 6, n = f & 63;
        a_s[k][n] = attn[((size_t)(b * Kd + k)) * Nd + n0 + n];
    }
    __syncthreads();
    float amu[8], as2[8];
    #pragma unroll
    for (int k = 0; k < 8; ++k) { amu[k] = 0.0f; as2[k] = 0.0f; }
    const float* vb = vals + ((size_t)b * Nd + n0) * Dd + tid;
    for (int n4 = 0; n4 < NCHUNK / 4; ++n4) {
        float4 a4[8];
        #pragma unroll
        for (int k = 0; k < 8; ++k) a4[k] = ((const float4*)&a_s[k][0])[n4];
        #pragma unroll
        for (int j = 0; j < 4; ++j) {
            const float v = vb[(size_t)(n4 * 4 + j) * Dd];
            const float v2 = v * v;
            #pragma unroll
            for (int k = 0; k < 8; ++k) {
                const float a = ((const float*)&a4[k])[j];
                amu[k] += a * v;
                as2[k] += a * v2;
            }
        }
    }
    #pragma unroll
    for (int k = 0; k < 8; ++k) {
        const size_t o = (((size_t)(b * NSPLIT + s)) * Kd + k) * Dd + tid;
        part[o] = amu[k];
        part[PARTSZ + o] = as2[k];
    }
}

// ---------------------------------------------------------------------------
// reduce partials -> mu, sigma; next-iter w & cst; fused slots_out write.
__global__ __launch_bounds__(256) void k_prep(
        const float* __restrict__ part, float* __restrict__ w_ws,
        float* __restrict__ cst_ws, const float* __restrict__ nzf,
        float* __restrict__ slots_out) {
    __shared__ float red[256];
    const int bk = blockIdx.x;
    const int b = bk >> 3, k = bk & 7, d = threadIdx.x;
    float mu = 0.0f, s2 = 0.0f;
    for (int s = 0; s < NSPLIT; ++s) {
        const size_t o = (((size_t)(b * NSPLIT + s)) * Kd + k) * Dd + d;
        mu += part[o];
        s2 += part[PARTSZ + o];
    }
    const float sg = s2 - mu * mu;
    w_ws[(size_t)bk * Dd + d] = 1.0f / (sg * sg + EPSf);
    red[d] = logf(fabsf(sg) + EPSf);
    slots_out[(size_t)bk * Dd + d] = mu + fmaxf(fabsf(sg), EPSf) * nzf[(size_t)bk * Dd + d];
    __syncthreads();
    for (int s = 128; s; s >>= 1) {
        if (d < s) red[d] += red[d + s];
        __syncthreads();
    }
    if (d == 0) cst_ws[bk] = LOGNORM - 0.5f * red[0];
}

// ---------------------------------------------------------------------------
extern "C" void kernel_launch(void* const* d_in, const int* in_sizes, int n_in,
                              void* d_out, int out_size, void* d_ws, size_t ws_size,
                              hipStream_t stream) {
    const float* emb  = (const float*)d_in[0];
    const float* mu0  = (const float*)d_in[1];
    const float* lsig = (const float*)d_in[2];
    // d_in[3] mixing_coeffs: cancels in softmax over N.
    const float* Wq   = (const float*)d_in[4];
    const float* Wk   = (const float*)d_in[5];
    const float* Wv   = (const float*)d_in[6];
    const float* lns  = (const float*)d_in[7];
    const float* lnb  = (const float*)d_in[8];
    const float* nz0  = (const float*)d_in[9];
    const float* nzf  = (const float*)d_in[10];
    // d_in[11] num_iterations == 3.

    float* ws    = (float*)d_ws;
    float* out   = (float*)d_out;
    float* keys  = ws + KEYS_OFF;
    float* vals  = ws + VALS_OFF;
    float* gllb  = ws + GLL_OFF;
    float* qws   = ws + Q_OFF;
    float* wws   = ws + W_OFF;
    float* cstw  = ws + CST_OFF;
    float* partw = ws + PART_OFF;
    ushort_t* Whp = (ushort_t*)(ws + WH_OFF);
    ushort_t* Wlp = (ushort_t*)(ws + WL_OFF);
    ushort_t* xhp = (ushort_t*)(ws + XH_OFF);
    ushort_t* xlp = (ushort_t*)(ws + XL_OFF);
    float* attn = out + Bd * Kd * Dd;   // (B,K,N) region of d_out

    k_lnprep<<<1024, 256, 0, stream>>>(emb, lns, lnb, xhp, xlp);
    k_wsplit<<<512, 256, 0, stream>>>(Wk, Wv, Whp, Wlp);
    k_gemm<<<dim3(256, 2), 256, 0, stream>>>(xhp, xlp, Whp, Wlp, keys, vals);
    k_init<<<64, 256, 0, stream>>>(mu0, lsig, nz0, Wq, qws, wws, cstw);
    for (int it = 0; it < NITER; ++it) {
        k_gll<<<512, 256, 0, stream>>>(keys, qws, wws, cstw, gllb);
        k_softmax<<<64, 1024, 0, stream>>>(gllb, attn);
        k_mus2<<<512, 256, 0, stream>>>(vals, attn, partw);
        k_prep<<<64, 256, 0, stream>>>(partw, wws, cstw, nzf, out);
    }
    (void)in_sizes; (void)n_in; (void)out_size; (void)ws_size;
}